// Round 9
// baseline (133.069 us; speedup 1.0000x reference)
//
#include <hip/hip_runtime.h>

#define B_  4
#define N_  4096
#define K_  32
#define C_  64
#define DH_ 128
#define PPW 8

typedef _Float16 half2v __attribute__((ext_vector_type(2)));
typedef _Float16 half8  __attribute__((ext_vector_type(8)));
typedef __fp16   fp16x2 __attribute__((ext_vector_type(2)));
typedef float  floatx16 __attribute__((ext_vector_type(16)));
typedef unsigned int uint_t;

union HU { half2v h; uint_t u; };
union HU2 { fp16x2 h; uint_t u; };

__device__ __forceinline__ uint_t pk2(float a, float b) {
    HU2 x; x.h = __builtin_amdgcn_cvt_pkrtz(a, b);   // v_cvt_pkrtz_f16_f32
    return x.u;
}

// ---------------------------------------------------------------------------
// Kernel 1: prep. 1024 blocks x 256 thr; block = (b = blk>>8, 16-pt tile).
//  Side jobs: xyz copy (1024*48) + Bpack (1024*16, (W_h*s_h) f16 B-frag order).
//  Main: Pgv = feats·W_gv^T (16n x 64o x 64c, both operands LDS-staged), then
//   QsH [n] f16x2 (words 0..31 gu-center | 32..63 gv-center), affine folded
//   PcatH[n] f16x2 (neighbor halves), scale folded
// ---------------------------------------------------------------------------
__global__ __launch_bounds__(256) void k_prep(
    const float* __restrict__ xyz,
    const float* __restrict__ features,
    const float* __restrict__ W_gv,
    const float* __restrict__ W_gu,
    const float* __restrict__ s_gu, const float* __restrict__ b_gu,
    const float* __restrict__ s_gv, const float* __restrict__ b_gv,
    const float* __restrict__ W_h,  const float* __restrict__ s_h,
    float* __restrict__ out_xyz,
    _Float16* __restrict__ Bpack,
    uint_t* __restrict__ QsH,
    uint_t* __restrict__ PcatH)
{
    const int blk = blockIdx.x;
    const int b   = blk >> 8;
    const int n0  = (blk & 255) * 16;
    const int t   = threadIdx.x;

    // side job A: xyz copy (output 0 of the tuple). 1024*48 = 49152.
    if (t < 48) { int e = blk*48 + t; out_xyz[e] = xyz[e]; }
    // side job B: Bpack. 1024*16 = 16384.
    if (t >= 64 && t < 80) {
        int e = blk*16 + (t - 64);
        int j = e & 7, l = (e >> 3) & 63, c = (e >> 9) & 7, ob = e >> 12;
        int o = ob*32 + (l & 31);
        int i = c*16 + (l >> 5)*8 + j;
        Bpack[e] = (_Float16)(W_h[o*DH_ + i] * s_h[o]);
    }

    __shared__ __align__(16) float ftile[64 * 17];   // [c][n], stride 17
    __shared__ __align__(16) float wtile[64 * 68];   // [c][o], stride 68

    {   // features tile: 64c x 16n, one float4/thread
        const int c = t >> 2, nq = t & 3;
        const float4 f4 = *(const float4*)&features[(b*C_ + c)*N_ + n0 + nq*4];
        ftile[c*17 + nq*4 + 0] = f4.x;
        ftile[c*17 + nq*4 + 1] = f4.y;
        ftile[c*17 + nq*4 + 2] = f4.z;
        ftile[c*17 + nq*4 + 3] = f4.w;
    }
#pragma unroll
    for (int r = 0; r < 4; r++) {    // W_gv transposed: [c][o]
        const int e4 = r*256 + t, o = e4 >> 4, c0 = (e4 & 15)*4;
        const float4 w4 = *(const float4*)&W_gv[o*C_ + c0];
        wtile[(c0+0)*68 + o] = w4.x;
        wtile[(c0+1)*68 + o] = w4.y;
        wtile[(c0+2)*68 + o] = w4.z;
        wtile[(c0+3)*68 + o] = w4.w;
    }
    __syncthreads();

    const int n  = t >> 4;       // 0..15
    const int oq = t & 15;       // o-chunk of 4
    const int o0 = oq * 4;

    float acc[4] = {};
#pragma unroll 4
    for (int c = 0; c < 64; c++) {
        const float a = ftile[c*17 + n];            // 16-lane broadcast
        const float4 wv = *(const float4*)&wtile[c*68 + o0];
        acc[0] = fmaf(a, wv.x, acc[0]);
        acc[1] = fmaf(a, wv.y, acc[1]);
        acc[2] = fmaf(a, wv.z, acc[2]);
        acc[3] = fmaf(a, wv.w, acc[3]);
    }

    const int bn = b*N_ + n0 + n;
    const float x0 = xyz[bn*3+0], x1 = xyz[bn*3+1], x2 = xyz[bn*3+2];

    const float4 sgu = *(const float4*)&s_gu[o0];
    const float4 bgu = *(const float4*)&b_gu[o0];
    const float4 sgv = *(const float4*)&s_gv[o0];
    const float4 bgv = *(const float4*)&b_gv[o0];

    float q[4], r[4];
#pragma unroll
    for (int jj = 0; jj < 4; jj++) {
        const int o = o0 + jj;
        q[jj] = x0*W_gu[o*6+0] + x1*W_gu[o*6+1] + x2*W_gu[o*6+2];
        r[jj] = x0*W_gu[o*6+3] + x1*W_gu[o*6+4] + x2*W_gu[o*6+5];
    }
    uint2 qa, pa;
    // gu half (words 0..31)
    qa.x = pk2(q[0]*sgu.x+bgu.x, q[1]*sgu.y+bgu.y);
    qa.y = pk2(q[2]*sgu.z+bgu.z, q[3]*sgu.w+bgu.w);
    pa.x = pk2(r[0]*sgu.x, r[1]*sgu.y);
    pa.y = pk2(r[2]*sgu.z, r[3]*sgu.w);
    *(uint2*)&QsH  [bn*64 + oq*2] = qa;
    *(uint2*)&PcatH[bn*64 + oq*2] = pa;
    // gv half (words 32..63)
    qa.x = pk2(acc[0]*sgv.x+bgv.x, acc[1]*sgv.y+bgv.y);
    qa.y = pk2(acc[2]*sgv.z+bgv.z, acc[3]*sgv.w+bgv.w);
    pa.x = pk2(acc[0]*sgv.x, acc[1]*sgv.y);
    pa.y = pk2(acc[2]*sgv.z, acc[3]*sgv.w);
    *(uint2*)&QsH  [bn*64 + 32 + oq*2] = qa;
    *(uint2*)&PcatH[bn*64 + 32 + oq*2] = pa;
}

// ---------------------------------------------------------------------------
// Kernel 2: fused main + f-layer. Block = 128 thr = 2 waves, one point-stream.
//  Wave oh handles o-half oh (2 o-blocks of 32, Bf resident). Fuse is
//  double-buffered; wave oh writes rows [oh*16, oh*16+16). ONE barrier per
//  point; gathers for p+1 issue at iteration top and are consumed by the
//  LDS-write step BEFORE the barrier -> vmcnt ~0 at every barrier, gather
//  latency hidden under MFMA+pool. f-layer + residual after the loop.
// ---------------------------------------------------------------------------
__global__ __launch_bounds__(128) void k_main(
    const int*      __restrict__ idx,
    const uint_t*   __restrict__ QsH,
    const uint_t*   __restrict__ PcatH,
    const _Float16* __restrict__ Bpack,
    const float*    __restrict__ b_h,
    const float*    __restrict__ W_f,
    const float*    __restrict__ s_f, const float* __restrict__ b_f,
    const float*    __restrict__ features,
    float* __restrict__ outF)
{
    const int t    = threadIdx.x;
    const int oh   = t >> 6;     // wave = o-half
    const int lane = t & 63;
    const int m    = lane & 31;
    const int hh   = lane >> 5;

    __shared__ uint_t fuse[2][32 * 66];                 // double buffer
    __shared__ __align__(16) float pooled[PPW * 132];

    half8 Bf[2][8];
#pragma unroll
    for (int ob = 0; ob < 2; ob++)
#pragma unroll
        for (int c = 0; c < 8; c++)
            Bf[ob][c] = *(const half8*)&Bpack[(((oh*2 + ob)*8 + c)*64 + lane)*8];

    const float bh0 = b_h[(oh*2+0)*32 + m];
    const float bh1 = b_h[(oh*2+1)*32 + m];

    const int bnb   = blockIdx.x * PPW;
    const int base0 = bnb & ~(N_ - 1);                  // b*N_
    const half2v zero2 = {(_Float16)0.f, (_Float16)0.f};

    // preload idx rows: lane m holds idx[n_p][m] (dup across halves)
    int jall[PPW];
#pragma unroll
    for (int p = 0; p < PPW; p++)
        jall[p] = idx[((bnb + p) & (N_-1))*K_ + m];

    // prologue: gather + write fuse[0] for point 0 (this wave's 16 rows)
    {
        const uint_t qw = QsH[(size_t)(bnb+0)*64 + lane];
        uint_t pg[16];
#pragma unroll
        for (int it = 0; it < 16; it++) {
            const int row = oh*16 + it;
            const int j   = __shfl(jall[0], row);       // wave-uniform
            pg[it] = PcatH[(size_t)(base0 + j)*64 + lane];
        }
#pragma unroll
        for (int it = 0; it < 16; it++) {
            HU a, pval; a.u = qw; pval.u = pg[it];
            half2v v = a.h + pval.h;
            v = __builtin_elementwise_max(v, zero2);
            HU o2; o2.h = v;
            fuse[0][(oh*16 + it)*66 + lane] = o2.u;
        }
    }
    __syncthreads();

    for (int p = 0; p < PPW; p++) {
        const int cur = p & 1, nxt = cur ^ 1;

        // ---- A: issue gathers for p+1 (land during MFMA below) ----
        uint_t pg[16]; uint_t qw_n = 0;
        if (p + 1 < PPW) {
            qw_n = QsH[(size_t)(bnb + p + 1)*64 + lane];
#pragma unroll
            for (int it = 0; it < 16; it++) {
                const int row = oh*16 + it;
                const int j   = __shfl(jall[p+1], row);
                pg[it] = PcatH[(size_t)(base0 + j)*64 + lane];
            }
        }

        // ---- B: MFMA + pool on fuse[cur] ----
        floatx16 acc0 = {}, acc1 = {};
#pragma unroll
        for (int c = 0; c < 8; c++) {
            const int wb = m*66 + c*8 + hh*4;
            union { uint_t u[4]; half8 h; } av;
            *(uint2*)&av.u[0] = *(const uint2*)&fuse[cur][wb];
            *(uint2*)&av.u[2] = *(const uint2*)&fuse[cur][wb + 2];
            acc0 = __builtin_amdgcn_mfma_f32_32x32x16_f16(av.h, Bf[0][c], acc0, 0, 0, 0);
            acc1 = __builtin_amdgcn_mfma_f32_32x32x16_f16(av.h, Bf[1][c], acc1, 0, 0, 0);
        }
        float v0 = 0.f, v1 = 0.f;
#pragma unroll
        for (int rg = 0; rg < 16; rg++) {
            v0 += fmaxf(acc0[rg] + bh0, 0.f);
            v1 += fmaxf(acc1[rg] + bh1, 0.f);
        }
        v0 += __shfl_xor(v0, 32);
        v1 += __shfl_xor(v1, 32);
        if (hh == 0) {
            pooled[p*132 + (oh*2+0)*32 + m] = v0;
            pooled[p*132 + (oh*2+1)*32 + m] = v1;
        }

        // ---- C: write fuse[nxt] from gathered regs (consumes vmcnt) ----
        if (p + 1 < PPW) {
#pragma unroll
            for (int it = 0; it < 16; it++) {
                HU a, pval; a.u = qw_n; pval.u = pg[it];
                half2v v = a.h + pval.h;
                v = __builtin_elementwise_max(v, zero2);
                HU o2; o2.h = v;
                fuse[nxt][(oh*16 + it)*66 + lane] = o2.u;
            }
        }
        // ---- D: barrier (no vmem outstanding here) ----
        __syncthreads();
    }

    // ---- f layer + residual for the block's 8 points ----
    const int b   = bnb >> 12;
    const int n0  = bnb & (N_ - 1);
    const int c   = t >> 1;      // 0..63
    const int r2  = t & 1;       // 4 n's per thread

    float acc[4] = {};
#pragma unroll 4
    for (int i0 = 0; i0 < DH_; i0 += 4) {
        const float4 wv = *(const float4*)&W_f[c*DH_ + i0];
#pragma unroll
        for (int r = 0; r < 4; r++) {
            const float4 p4 = *(const float4*)&pooled[(r2*4 + r)*132 + i0];
            acc[r] += wv.x*p4.x + wv.y*p4.y + wv.z*p4.z + wv.w*p4.w;
        }
    }
    const float sfc = s_f[c] * (1.f/(float)K_);
    const float bfc = b_f[c];
    const float4 fr = *(const float4*)&features[(b*C_ + c)*N_ + n0 + r2*4];
    float4 ov;
    ov.x = fmaxf(acc[0]*sfc + bfc, 0.f) + fr.x;
    ov.y = fmaxf(acc[1]*sfc + bfc, 0.f) + fr.y;
    ov.z = fmaxf(acc[2]*sfc + bfc, 0.f) + fr.z;
    ov.w = fmaxf(acc[3]*sfc + bfc, 0.f) + fr.w;
    *(float4*)&outF[(b*C_ + c)*N_ + n0 + r2*4] = ov;
}

// ---------------------------------------------------------------------------
extern "C" void kernel_launch(void* const* d_in, const int* in_sizes, int n_in,
                              void* d_out, int out_size, void* d_ws, size_t ws_size,
                              hipStream_t stream)
{
    const float* xyz      = (const float*)d_in[0];
    const float* features = (const float*)d_in[1];
    const int*   idx      = (const int*)  d_in[2];
    const float* W_gu     = (const float*)d_in[3];
    const float* s_gu     = (const float*)d_in[4];
    const float* b_gu     = (const float*)d_in[5];
    const float* W_gv     = (const float*)d_in[6];
    const float* s_gv     = (const float*)d_in[7];
    const float* b_gv     = (const float*)d_in[8];
    const float* W_h      = (const float*)d_in[9];
    const float* s_h      = (const float*)d_in[10];
    const float* b_h      = (const float*)d_in[11];
    const float* W_f      = (const float*)d_in[12];
    const float* s_f      = (const float*)d_in[13];
    const float* b_f      = (const float*)d_in[14];

    float* out  = (float*)d_out;          // tuple: xyz first, then out
    float* outF = out + B_*N_*3;

    // workspace carve (~8.1 MB)
    char* wp = (char*)d_ws;
    uint_t*   QsH   = (uint_t*)wp;   wp += (size_t)B_*N_*64*4;    // 4 MB
    uint_t*   PcatH = (uint_t*)wp;   wp += (size_t)B_*N_*64*4;    // 4 MB
    _Float16* Bpack = (_Float16*)wp; wp += DH_*DH_*2;             // 32 KB

    k_prep<<<B_*(N_/16), 256, 0, stream>>>(xyz, features, W_gv, W_gu,
                                           s_gu, b_gu, s_gv, b_gv, W_h, s_h,
                                           out, Bpack, QsH, PcatH);
    k_main<<<(B_*N_)/PPW, 128, 0, stream>>>(idx, QsH, PcatH, Bpack, b_h,
                                            W_f, s_f, b_f, features, outF);
}

// Round 10
// 129.472 us; speedup vs baseline: 1.0278x; 1.0278x over previous
//
#include <hip/hip_runtime.h>

#define B_  4
#define N_  4096
#define K_  32
#define C_  64
#define DH_ 128
#define PPW 8

typedef _Float16 half2v __attribute__((ext_vector_type(2)));
typedef _Float16 half8  __attribute__((ext_vector_type(8)));
typedef __fp16   fp16x2 __attribute__((ext_vector_type(2)));
typedef float  floatx16 __attribute__((ext_vector_type(16)));
typedef unsigned int uint_t;

union HU { half2v h; uint_t u; };
union HU2 { fp16x2 h; uint_t u; };

__device__ __forceinline__ uint_t pk2(float a, float b) {
    HU2 x; x.h = __builtin_amdgcn_cvt_pkrtz(a, b);   // v_cvt_pkrtz_f16_f32
    return x.u;
}

// ---------------------------------------------------------------------------
// Kernel 1: prep. UNCHANGED from R9 (frozen).
// ---------------------------------------------------------------------------
__global__ __launch_bounds__(256) void k_prep(
    const float* __restrict__ xyz,
    const float* __restrict__ features,
    const float* __restrict__ W_gv,
    const float* __restrict__ W_gu,
    const float* __restrict__ s_gu, const float* __restrict__ b_gu,
    const float* __restrict__ s_gv, const float* __restrict__ b_gv,
    const float* __restrict__ W_h,  const float* __restrict__ s_h,
    float* __restrict__ out_xyz,
    _Float16* __restrict__ Bpack,
    uint_t* __restrict__ QsH,
    uint_t* __restrict__ PcatH)
{
    const int blk = blockIdx.x;
    const int b   = blk >> 8;
    const int n0  = (blk & 255) * 16;
    const int t   = threadIdx.x;

    if (t < 48) { int e = blk*48 + t; out_xyz[e] = xyz[e]; }
    if (t >= 64 && t < 80) {
        int e = blk*16 + (t - 64);
        int j = e & 7, l = (e >> 3) & 63, c = (e >> 9) & 7, ob = e >> 12;
        int o = ob*32 + (l & 31);
        int i = c*16 + (l >> 5)*8 + j;
        Bpack[e] = (_Float16)(W_h[o*DH_ + i] * s_h[o]);
    }

    __shared__ __align__(16) float ftile[64 * 17];   // [c][n], stride 17
    __shared__ __align__(16) float wtile[64 * 68];   // [c][o], stride 68

    {
        const int c = t >> 2, nq = t & 3;
        const float4 f4 = *(const float4*)&features[(b*C_ + c)*N_ + n0 + nq*4];
        ftile[c*17 + nq*4 + 0] = f4.x;
        ftile[c*17 + nq*4 + 1] = f4.y;
        ftile[c*17 + nq*4 + 2] = f4.z;
        ftile[c*17 + nq*4 + 3] = f4.w;
    }
#pragma unroll
    for (int r = 0; r < 4; r++) {
        const int e4 = r*256 + t, o = e4 >> 4, c0 = (e4 & 15)*4;
        const float4 w4 = *(const float4*)&W_gv[o*C_ + c0];
        wtile[(c0+0)*68 + o] = w4.x;
        wtile[(c0+1)*68 + o] = w4.y;
        wtile[(c0+2)*68 + o] = w4.z;
        wtile[(c0+3)*68 + o] = w4.w;
    }
    __syncthreads();

    const int n  = t >> 4;
    const int oq = t & 15;
    const int o0 = oq * 4;

    float acc[4] = {};
#pragma unroll 4
    for (int c = 0; c < 64; c++) {
        const float a = ftile[c*17 + n];
        const float4 wv = *(const float4*)&wtile[c*68 + o0];
        acc[0] = fmaf(a, wv.x, acc[0]);
        acc[1] = fmaf(a, wv.y, acc[1]);
        acc[2] = fmaf(a, wv.z, acc[2]);
        acc[3] = fmaf(a, wv.w, acc[3]);
    }

    const int bn = b*N_ + n0 + n;
    const float x0 = xyz[bn*3+0], x1 = xyz[bn*3+1], x2 = xyz[bn*3+2];

    const float4 sgu = *(const float4*)&s_gu[o0];
    const float4 bgu = *(const float4*)&b_gu[o0];
    const float4 sgv = *(const float4*)&s_gv[o0];
    const float4 bgv = *(const float4*)&b_gv[o0];

    float q[4], r[4];
#pragma unroll
    for (int jj = 0; jj < 4; jj++) {
        const int o = o0 + jj;
        q[jj] = x0*W_gu[o*6+0] + x1*W_gu[o*6+1] + x2*W_gu[o*6+2];
        r[jj] = x0*W_gu[o*6+3] + x1*W_gu[o*6+4] + x2*W_gu[o*6+5];
    }
    uint2 qa, pa;
    qa.x = pk2(q[0]*sgu.x+bgu.x, q[1]*sgu.y+bgu.y);
    qa.y = pk2(q[2]*sgu.z+bgu.z, q[3]*sgu.w+bgu.w);
    pa.x = pk2(r[0]*sgu.x, r[1]*sgu.y);
    pa.y = pk2(r[2]*sgu.z, r[3]*sgu.w);
    *(uint2*)&QsH  [bn*64 + oq*2] = qa;
    *(uint2*)&PcatH[bn*64 + oq*2] = pa;
    qa.x = pk2(acc[0]*sgv.x+bgv.x, acc[1]*sgv.y+bgv.y);
    qa.y = pk2(acc[2]*sgv.z+bgv.z, acc[3]*sgv.w+bgv.w);
    pa.x = pk2(acc[0]*sgv.x, acc[1]*sgv.y);
    pa.y = pk2(acc[2]*sgv.z, acc[3]*sgv.w);
    *(uint2*)&QsH  [bn*64 + 32 + oq*2] = qa;
    *(uint2*)&PcatH[bn*64 + 32 + oq*2] = pa;
}

// ---------------------------------------------------------------------------
// Kernel 2: fused main + f-layer. Block = 128 thr = 2 waves.
//  R9 structure (double-buffered fuse, 1 barrier/point) with SCALAR idx:
//  ohu = readfirstlane(wave) makes idx-row addresses wave-uniform ->
//  s_load_dwordx16 puts the 16 row-j's in SGPRs; gathers become
//  global_load_dword v,v(lane*4),s[rowbase] with zero bpermute / zero VALU
//  address math. LDS addressing reduces to const v_addr + offset imm.
// ---------------------------------------------------------------------------
__global__ __launch_bounds__(128) void k_main(
    const int*      __restrict__ idx,
    const uint_t*   __restrict__ QsH,
    const uint_t*   __restrict__ PcatH,
    const _Float16* __restrict__ Bpack,
    const float*    __restrict__ b_h,
    const float*    __restrict__ W_f,
    const float*    __restrict__ s_f, const float* __restrict__ b_f,
    const float*    __restrict__ features,
    float* __restrict__ outF)
{
    const int t    = threadIdx.x;
    const int ohu  = __builtin_amdgcn_readfirstlane(t >> 6);   // wave o-half (SGPR)
    const int lane = t & 63;
    const int m    = lane & 31;
    const int hh   = lane >> 5;

    __shared__ uint_t fuse[2][32 * 66];                 // double buffer
    __shared__ __align__(16) float pooled[PPW * 132];

    half8 Bf[2][8];
#pragma unroll
    for (int ob = 0; ob < 2; ob++)
#pragma unroll
        for (int c = 0; c < 8; c++)
            Bf[ob][c] = *(const half8*)&Bpack[(((ohu*2 + ob)*8 + c)*64 + lane)*8];

    const float bh0 = b_h[(ohu*2+0)*32 + m];
    const float bh1 = b_h[(ohu*2+1)*32 + m];

    const int bnb   = blockIdx.x * PPW;
    const int base0 = bnb & ~(N_ - 1);                  // b*N_
    const half2v zero2 = {(_Float16)0.f, (_Float16)0.f};

    uint_t pg[16];
    uint_t qw;
    int js[16];

    // prologue: scalar idx row for p0, gather p0, build fuse[0]
    {
        const int n0p = bnb & (N_ - 1);
        const int* ip = idx + n0p*K_ + ohu*16;          // uniform -> s_load
#pragma unroll
        for (int it = 0; it < 16; it++) js[it] = ip[it];
        qw = QsH[(size_t)bnb*64 + lane];
#pragma unroll
        for (int it = 0; it < 16; it++)
            pg[it] = PcatH[((size_t)(base0 + js[it]) << 6) + lane];
#pragma unroll
        for (int it = 0; it < 16; it++) {
            HU a, pval; a.u = qw; pval.u = pg[it];
            half2v v = a.h + pval.h;
            v = __builtin_elementwise_max(v, zero2);
            HU o2; o2.h = v;
            fuse[0][(ohu*16 + it)*66 + lane] = o2.u;
        }
    }
    __syncthreads();

#pragma unroll
    for (int p = 0; p < PPW; p++) {
        const int cur = p & 1, nxt = cur ^ 1;

        // ---- A: scalar idx row + gathers for p+1 (land during MFMA) ----
        uint_t qw_n = 0;
        if (p + 1 < PPW) {
            const int np = (bnb + p + 1) & (N_ - 1);
            const int* ip = idx + np*K_ + ohu*16;       // uniform -> s_load
#pragma unroll
            for (int it = 0; it < 16; it++) js[it] = ip[it];
            qw_n = QsH[(size_t)(bnb + p + 1)*64 + lane];
#pragma unroll
            for (int it = 0; it < 16; it++)
                pg[it] = PcatH[((size_t)(base0 + js[it]) << 6) + lane];
        }

        // ---- B: MFMA + pool on fuse[cur] ----
        floatx16 acc0 = {}, acc1 = {};
#pragma unroll
        for (int c = 0; c < 8; c++) {
            const int wb = m*66 + c*8 + hh*4;
            union { uint_t u[4]; half8 h; } av;
            *(uint2*)&av.u[0] = *(const uint2*)&fuse[cur][wb];
            *(uint2*)&av.u[2] = *(const uint2*)&fuse[cur][wb + 2];
            acc0 = __builtin_amdgcn_mfma_f32_32x32x16_f16(av.h, Bf[0][c], acc0, 0, 0, 0);
            acc1 = __builtin_amdgcn_mfma_f32_32x32x16_f16(av.h, Bf[1][c], acc1, 0, 0, 0);
        }
        float v0 = 0.f, v1 = 0.f;
#pragma unroll
        for (int rg = 0; rg < 16; rg++) {
            v0 += fmaxf(acc0[rg] + bh0, 0.f);
            v1 += fmaxf(acc1[rg] + bh1, 0.f);
        }
        v0 += __shfl_xor(v0, 32);
        v1 += __shfl_xor(v1, 32);
        if (hh == 0) {
            pooled[p*132 + (ohu*2+0)*32 + m] = v0;
            pooled[p*132 + (ohu*2+1)*32 + m] = v1;
        }

        // ---- C: build fuse[nxt] from gathered regs ----
        if (p + 1 < PPW) {
#pragma unroll
            for (int it = 0; it < 16; it++) {
                HU a, pval; a.u = qw_n; pval.u = pg[it];
                half2v v = a.h + pval.h;
                v = __builtin_elementwise_max(v, zero2);
                HU o2; o2.h = v;
                fuse[nxt][(ohu*16 + it)*66 + lane] = o2.u;
            }
        }
        // ---- D: one barrier per point ----
        __syncthreads();
    }

    // ---- f layer + residual for the block's 8 points ----
    const int b   = bnb >> 12;
    const int n0  = bnb & (N_ - 1);
    const int c   = t >> 1;      // 0..63
    const int r2  = t & 1;       // 4 n's per thread

    float acc[4] = {};
#pragma unroll 4
    for (int i0 = 0; i0 < DH_; i0 += 4) {
        const float4 wv = *(const float4*)&W_f[c*DH_ + i0];
#pragma unroll
        for (int r = 0; r < 4; r++) {
            const float4 p4 = *(const float4*)&pooled[(r2*4 + r)*132 + i0];
            acc[r] += wv.x*p4.x + wv.y*p4.y + wv.z*p4.z + wv.w*p4.w;
        }
    }
    const float sfc = s_f[c] * (1.f/(float)K_);
    const float bfc = b_f[c];
    const float4 fr = *(const float4*)&features[(b*C_ + c)*N_ + n0 + r2*4];
    float4 ov;
    ov.x = fmaxf(acc[0]*sfc + bfc, 0.f) + fr.x;
    ov.y = fmaxf(acc[1]*sfc + bfc, 0.f) + fr.y;
    ov.z = fmaxf(acc[2]*sfc + bfc, 0.f) + fr.z;
    ov.w = fmaxf(acc[3]*sfc + bfc, 0.f) + fr.w;
    *(float4*)&outF[(b*C_ + c)*N_ + n0 + r2*4] = ov;
}

// ---------------------------------------------------------------------------
extern "C" void kernel_launch(void* const* d_in, const int* in_sizes, int n_in,
                              void* d_out, int out_size, void* d_ws, size_t ws_size,
                              hipStream_t stream)
{
    const float* xyz      = (const float*)d_in[0];
    const float* features = (const float*)d_in[1];
    const int*   idx      = (const int*)  d_in[2];
    const float* W_gu     = (const float*)d_in[3];
    const float* s_gu     = (const float*)d_in[4];
    const float* b_gu     = (const float*)d_in[5];
    const float* W_gv     = (const float*)d_in[6];
    const float* s_gv     = (const float*)d_in[7];
    const float* b_gv     = (const float*)d_in[8];
    const float* W_h      = (const float*)d_in[9];
    const float* s_h      = (const float*)d_in[10];
    const float* b_h      = (const float*)d_in[11];
    const float* W_f      = (const float*)d_in[12];
    const float* s_f      = (const float*)d_in[13];
    const float* b_f      = (const float*)d_in[14];

    float* out  = (float*)d_out;          // tuple: xyz first, then out
    float* outF = out + B_*N_*3;

    // workspace carve (~8.1 MB)
    char* wp = (char*)d_ws;
    uint_t*   QsH   = (uint_t*)wp;   wp += (size_t)B_*N_*64*4;    // 4 MB
    uint_t*   PcatH = (uint_t*)wp;   wp += (size_t)B_*N_*64*4;    // 4 MB
    _Float16* Bpack = (_Float16*)wp; wp += DH_*DH_*2;             // 32 KB

    k_prep<<<B_*(N_/16), 256, 0, stream>>>(xyz, features, W_gv, W_gu,
                                           s_gu, b_gu, s_gv, b_gv, W_h, s_h,
                                           out, Bpack, QsH, PcatH);
    k_main<<<(B_*N_)/PPW, 128, 0, stream>>>(idx, QsH, PcatH, Bpack, b_h,
                                            W_f, s_f, b_f, features, outF);
}